// Round 1
// baseline (130.741 us; speedup 1.0000x reference)
//
#include <hip/hip_runtime.h>

#define KSZ 7
#define PAD 3
#define HH 320
#define WW 1024
#define BB 8
#define TH 32
#define TW 64
#define HALO_H (TH + 2*PAD)   // 38
#define HALO_W (TW + 2*PAD)   // 70
#define LDS_W  72             // padded stride (avoid pow2)

// scale = 1 / (49 * B*H*W)
#define OUT_SCALE (1.0f / (49.0f * (float)(BB) * (float)(HH) * (float)(WW)))

__global__ __launch_bounds__(256) void ternary_loss_kernel(
    const float* __restrict__ x, const float* __restrict__ y,
    float* __restrict__ out)
{
    __shared__ float sIx[HALO_H][LDS_W];
    __shared__ float sIy[HALO_H][LDS_W];
    __shared__ float wave_sums[4];

    const int tile_j = blockIdx.x * TW;
    const int tile_i = blockIdx.y * TH;
    const int b      = blockIdx.z;
    const int tx  = threadIdx.x;            // 0..63 (one full wave per row)
    const int ty  = threadIdx.y;            // 0..3
    const int tid = ty * 64 + tx;

    const float* xb = x + (size_t)b * 3 * HH * WW;
    const float* yb = y + (size_t)b * 3 * HH * WW;

    // ---- stage intensity halo tile into LDS (zero-fill outside image) ----
    for (int idx = tid; idx < HALO_H * HALO_W; idx += 256) {
        int r = idx / HALO_W;
        int c = idx - r * HALO_W;
        int gi = tile_i - PAD + r;
        int gj = tile_j - PAD + c;
        float vx = 0.0f, vy = 0.0f;
        if (gi >= 0 && gi < HH && gj >= 0 && gj < WW) {
            size_t o = (size_t)gi * WW + gj;
            vx = (xb[o] + xb[(size_t)HH * WW + o] + xb[2 * (size_t)HH * WW + o]) * (1.0f / 3.0f);
            vy = (yb[o] + yb[(size_t)HH * WW + o] + yb[2 * (size_t)HH * WW + o]) * (1.0f / 3.0f);
        }
        sIx[r][c] = vx;
        sIy[r][c] = vy;
    }
    __syncthreads();

    // ---- per-thread compute: 8 pixels (rows ty+4k), 24 half-space offsets ----
    const int gj = tile_j + tx;
    // column interior masks for dj = -3..3 (loop-invariant over k)
    float colOK[7];
    #pragma unroll
    for (int d = 0; d < 7; ++d) {
        int nj = gj + d - 3;
        colOK[d] = (nj >= PAD && nj < WW - PAD) ? 1.0f : 0.0f;
    }

    float acc = 0.0f;

    #pragma unroll 1
    for (int k = 0; k < TH / 4; ++k) {
        const int li = ty + 4 * k;        // local row 0..31
        const int gi = tile_i + li;

        const float cx = sIx[li + PAD][tx + PAD];
        const float cy = sIy[li + PAD][tx + PAD];

        const float mc = (gi >= PAD && gi < HH - PAD && colOK[3] > 0.5f) ? 1.0f : 0.0f;

        float rowOK[4];
        #pragma unroll
        for (int di = 0; di < 4; ++di) {
            int ni = gi + di;
            rowOK[di] = (ni >= PAD && ni < HH - PAD) ? 1.0f : 0.0f;
        }

        #pragma unroll
        for (int di = 0; di <= 3; ++di) {
            #pragma unroll
            for (int dj = -3; dj <= 3; ++dj) {
                if (di == 0 && dj <= 0) continue;   // half-space: 24 offsets
                float nx = sIx[li + PAD + di][tx + PAD + dj];
                float ny = sIy[li + PAD + di][tx + PAD + dj];
                float dx = nx - cx;
                float gx = dx * __builtin_amdgcn_rsqf(fmaf(dx, dx, 0.81f));
                float dy = ny - cy;
                float gy = dy * __builtin_amdgcn_rsqf(fmaf(dy, dy, 0.81f));
                float t  = gx - gy;
                float t2 = t * t;
                float v  = t2 * __builtin_amdgcn_rcpf(t2 + 0.1f);
                float w  = mc + rowOK[di] * colOK[dj + 3];   // pair-trick weight
                acc = fmaf(v, w, acc);
            }
        }
    }

    // ---- reduction: wave shuffle -> LDS across 4 waves -> one atomic ----
    #pragma unroll
    for (int off = 32; off > 0; off >>= 1)
        acc += __shfl_down(acc, off, 64);
    if (tx == 0) wave_sums[ty] = acc;
    __syncthreads();
    if (tid == 0) {
        float total = wave_sums[0] + wave_sums[1] + wave_sums[2] + wave_sums[3];
        atomicAdd(out, total * OUT_SCALE);
    }
}

extern "C" void kernel_launch(void* const* d_in, const int* in_sizes, int n_in,
                              void* d_out, int out_size, void* d_ws, size_t ws_size,
                              hipStream_t stream) {
    const float* x = (const float*)d_in[0];
    const float* y = (const float*)d_in[1];
    float* out = (float*)d_out;

    hipMemsetAsync(out, 0, sizeof(float), stream);

    dim3 grid(WW / TW, HH / TH, BB);   // 16 x 10 x 8 = 1280 blocks
    dim3 block(64, 4, 1);
    ternary_loss_kernel<<<grid, block, 0, stream>>>(x, y, out);
}

// Round 2
// 125.857 us; speedup vs baseline: 1.0388x; 1.0388x over previous
//
#include <hip/hip_runtime.h>

#define PAD 3
#define HH 320
#define WW 1024
#define BB 8
#define TH 32
#define TW 64
#define HALO_H (TH + 2*PAD)   // 38
#define HALO_W (TW + 2*PAD)   // 70
#define LDS_W  72             // padded stride
#define RPW 8                 // rows per wave (TH / 4 waves)

#define NIN ((HH - 2*PAD) * (WW - 2*PAD))       // 314*1018 interior pixels per image
#define OUT_SCALE (1.0 / (49.0 * (double)BB * (double)HH * (double)WW))
// analytic constant: sum of pair-weights * 1  ->  48 * BB * NIN * OUT_SCALE
#define C0 ((float)(48.0 * (double)BB * (double)NIN * OUT_SCALE))
#define NEG_SCALE ((float)(-0.1 * OUT_SCALE))

__global__ __launch_bounds__(256) void ternary_loss_kernel(
    const float* __restrict__ x, const float* __restrict__ y,
    float* __restrict__ out)
{
    __shared__ float sIx[HALO_H][LDS_W];
    __shared__ float sIy[HALO_H][LDS_W];
    __shared__ float wave_sums[4];

    const int tile_j = blockIdx.x * TW;
    const int tile_i = blockIdx.y * TH;
    const int b      = blockIdx.z;
    const int tx  = threadIdx.x;            // 0..63 = column within tile
    const int wv  = threadIdx.y;            // 0..3  = wave id
    const int tid = wv * 64 + tx;

    const float* xb = x + (size_t)b * 3 * HH * WW;
    const float* yb = y + (size_t)b * 3 * HH * WW;

    // ---- stage intensity halo tile into LDS (zero-fill outside image) ----
    for (int idx = tid; idx < HALO_H * HALO_W; idx += 256) {
        int r = idx / HALO_W;
        int c = idx - r * HALO_W;
        int gi = tile_i - PAD + r;
        int gj = tile_j - PAD + c;
        float vx = 0.0f, vy = 0.0f;
        if (gi >= 0 && gi < HH && gj >= 0 && gj < WW) {
            size_t o = (size_t)gi * WW + gj;
            vx = (xb[o] + xb[(size_t)HH * WW + o] + xb[2 * (size_t)HH * WW + o]) * (1.0f / 3.0f);
            vy = (yb[o] + yb[(size_t)HH * WW + o] + yb[2 * (size_t)HH * WW + o]) * (1.0f / 3.0f);
        }
        sIx[r][c] = vx;
        sIy[r][c] = vy;
    }
    __syncthreads();

    // ---- per-lane column-interior flags (dj = -3..3 -> d = 0..6) ----
    const int gj = tile_j + tx;
    float colOK[7];
    #pragma unroll
    for (int d = 0; d < 7; ++d) {
        int nj = gj + d - 3;
        colOK[d] = (nj >= PAD && nj < WW - PAD) ? 1.0f : 0.0f;
    }

    // ---- rolling 4-row register window; this wave owns rows [li0, li0+8) ----
    const int li0 = wv * RPW;

    float wx[4][7], wy[4][7];
    // prologue: slots 0..2 <- staged rows li0+3 .. li0+5
    #pragma unroll
    for (int r = 0; r < 3; ++r) {
        #pragma unroll
        for (int d = 0; d < 7; ++d) {
            wx[r][d] = sIx[li0 + 3 + r][tx + d];
            wy[r][d] = sIy[li0 + 3 + r][tx + d];
        }
    }

    float acc = 0.0f;   // accumulates  sum of w * rcp(0.1 + t^2)

    #pragma unroll 1
    for (int io = 0; io < RPW / 4; ++io) {
        #pragma unroll
        for (int iu = 0; iu < 4; ++iu) {
            const int li = li0 + io * 4 + iu;      // local pixel row
            const int gi = tile_i + li;            // global pixel row
            const int snew = (iu + 3) & 3;         // slot for incoming row (staged li+6)
            #pragma unroll
            for (int d = 0; d < 7; ++d) {
                wx[snew][d] = sIx[li + 6][tx + d];
                wy[snew][d] = sIy[li + 6][tx + d];
            }

            float rin[4];
            #pragma unroll
            for (int di = 0; di < 4; ++di) {
                int ni = gi + di;
                rin[di] = (ni >= PAD && ni < HH - PAD) ? 1.0f : 0.0f;
            }
            const float mc = rin[0] * colOK[3];    // center-pixel mask

            const float cx = wx[iu & 3][3];
            const float cy = wy[iu & 3][3];

            #pragma unroll
            for (int di = 0; di <= 3; ++di) {
                const int s = (iu + di) & 3;
                #pragma unroll
                for (int dj = -3; dj <= 3; ++dj) {
                    if (di == 0 && dj <= 0) continue;   // half-space: 24 pairs
                    float nx = wx[s][dj + 3];
                    float ny = wy[s][dj + 3];
                    float dx = nx - cx;
                    float gx = dx * __builtin_amdgcn_rsqf(fmaf(dx, dx, 0.81f));
                    float dy = ny - cy;
                    float gy = dy * __builtin_amdgcn_rsqf(fmaf(dy, dy, 0.81f));
                    float t  = gx - gy;
                    float denom = fmaf(t, t, 0.1f);
                    float r = __builtin_amdgcn_rcpf(denom);
                    float w = fmaf(rin[di], colOK[dj + 3], mc);  // pair weight
                    acc = fmaf(w, r, acc);
                }
            }
        }
    }

    // ---- reduction: wave shuffle -> LDS across 4 waves -> one atomic ----
    #pragma unroll
    for (int off = 32; off > 0; off >>= 1)
        acc += __shfl_down(acc, off, 64);
    if (tx == 0) wave_sums[wv] = acc;
    __syncthreads();
    if (tid == 0) {
        float total = (wave_sums[0] + wave_sums[1] + wave_sums[2] + wave_sums[3]) * NEG_SCALE;
        if (blockIdx.x == 0 && blockIdx.y == 0 && blockIdx.z == 0)
            total += C0;                       // analytic  sum(w)*1  term, added once
        atomicAdd(out, total);
    }
}

extern "C" void kernel_launch(void* const* d_in, const int* in_sizes, int n_in,
                              void* d_out, int out_size, void* d_ws, size_t ws_size,
                              hipStream_t stream) {
    const float* x = (const float*)d_in[0];
    const float* y = (const float*)d_in[1];
    float* out = (float*)d_out;

    hipMemsetAsync(out, 0, sizeof(float), stream);

    dim3 grid(WW / TW, HH / TH, BB);   // 16 x 10 x 8 = 1280 blocks
    dim3 block(64, 4, 1);
    ternary_loss_kernel<<<grid, block, 0, stream>>>(x, y, out);
}